// Round 19
// baseline (544.638 us; speedup 1.0000x reference)
//
#include <hip/hip_runtime.h>
#include <hip/hip_bf16.h>
#include <stdint.h>
#include <stddef.h>

// ---------------- problem constants ----------------
#define B_TOT   2048        // windows total
#define NTOK    49          // tokens per window
#define CDIM    512
#define NHEAD   16
#define HD      32
#define NWIN    64          // windows per image
#define MROWS   (B_TOT*NTOK)   // 100352
#define O_QKV   1536
#define SCALE_F 0.17677669529663687f   // 32^-0.5

typedef short bf16x8 __attribute__((ext_vector_type(8)));
typedef float f32x4  __attribute__((ext_vector_type(4)));

__device__ __forceinline__ unsigned short f2bf(float f){
  union { float f; unsigned u; } v; v.f = f;
  unsigned r = v.u + 0x7fffu + ((v.u >> 16) & 1u);
  return (unsigned short)(r >> 16);
}
__device__ __forceinline__ unsigned pkbf(float a, float b){
  return (unsigned)f2bf(a) | ((unsigned)f2bf(b) << 16);
}

#define GL16(g,l) __builtin_amdgcn_global_load_lds( \
      (const __attribute__((address_space(1))) unsigned int*)(g), \
      (__attribute__((address_space(3))) unsigned int*)(l), 16, 0, 0)

// ---------------- prep: x->bf16, weights->bf16, fused bias+mask table ----------------
__global__ void k_prep(const float* __restrict__ x,
                       const float* __restrict__ qkv_w, const float* __restrict__ proj_w,
                       const float* __restrict__ rpb, const int* __restrict__ rel_idx,
                       const float* __restrict__ mask,
                       unsigned short* __restrict__ xb,
                       unsigned short* __restrict__ wqkv, unsigned short* __restrict__ wproj,
                       float* __restrict__ bmb){
  int i = blockIdx.x * blockDim.x + threadIdx.x;
  int st = gridDim.x * blockDim.x;
  const int n4 = MROWS * CDIM / 4;
  for (int j = i; j < n4; j += st){
    float4 v = ((const float4*)x)[j];
    uint2 o;
    o.x = pkbf(v.x, v.y);
    o.y = pkbf(v.z, v.w);
    ((uint2*)xb)[j] = o;
  }
  for (int j = i; j < O_QKV*CDIM; j += st) wqkv[j] = f2bf(qkv_w[j]);
  for (int j = i; j < CDIM*CDIM;  j += st) wproj[j] = f2bf(proj_w[j]);
  const int TOT = NWIN * NHEAD * NTOK * 64;
  for (int j = i; j < TOT; j += st){
    int wh  = j / (NTOK*64);
    int rem = j - wh * (NTOK*64);
    int qt  = rem >> 6, kt = rem & 63;
    int wi = wh >> 4, h = wh & 15;
    float v;
    if (kt < NTOK){
      int rc = qt * NTOK + kt;
      v = mask[wi * (NTOK*NTOK) + rc] + rpb[rel_idx[rc] * NHEAD + h];
    } else v = -1e30f;
    bmb[j] = v;
  }
}

// ---------------- 8-phase 256x256 GEMM (round-3 schedule, 4/4 validated) ----------------
#define LDA_(P,RG,MI,S) (*(const bf16x8*)(rA + (P)*32768 + (RG)*16384 + (MI)*2048 + ((S)?(cb0^64):cb0)))
#define LDB_(P,CG,NI,S) (*(const bf16x8*)(rB + (P)*32768 + (CG)*16384 + (NI)*2048 + ((S)?(cb0^64):cb0)))

#define STAGE_A(P,HG,KT) { \
    GL16(aS0 + (size_t)(HG)*64*Kb + (size_t)(KT)*128, ldA + (P)*32768 + (HG)*16384); \
    GL16(aS1 + (size_t)(HG)*64*Kb + (size_t)(KT)*128, ldA + (P)*32768 + (HG)*16384 + 8192); }
#define STAGE_B(P,HG,KT) { \
    GL16(bS0 + (size_t)(HG)*32*Kb + (size_t)(KT)*128, ldB + (P)*32768 + (HG)*16384); \
    GL16(bS1 + (size_t)(HG)*32*Kb + (size_t)(KT)*128, ldB + (P)*32768 + (HG)*16384 + 8192); }

#define PHASE(P,RG,CG,DOA,DOB,VM,...) { \
  if (DOA){ _Pragma("unroll") for (int mi=0;mi<4;++mi){ af[mi][0]=LDA_(P,RG,mi,0); af[mi][1]=LDA_(P,RG,mi,1);} } \
  if (DOB){ _Pragma("unroll") for (int ni=0;ni<2;++ni){ bf_[ni][0]=LDB_(P,CG,ni,0); bf_[ni][1]=LDB_(P,CG,ni,1);} } \
  __VA_ARGS__; \
  __builtin_amdgcn_s_barrier(); \
  asm volatile("s_waitcnt lgkmcnt(0)" ::: "memory"); \
  __builtin_amdgcn_sched_barrier(0); \
  __builtin_amdgcn_s_setprio(1); \
  _Pragma("unroll") for (int s=0;s<2;++s) \
    _Pragma("unroll") for (int mi=0;mi<4;++mi) \
      _Pragma("unroll") for (int ni=0;ni<2;++ni) \
        acc[(RG)*4+mi][(CG)*2+ni] = __builtin_amdgcn_mfma_f32_16x16x32_bf16(af[mi][s], bf_[ni][s], acc[(RG)*4+mi][(CG)*2+ni], 0,0,0); \
  __builtin_amdgcn_s_setprio(0); \
  if (VM) asm volatile("s_waitcnt vmcnt(4)" ::: "memory"); \
  __builtin_amdgcn_s_barrier(); \
  asm volatile("" ::: "memory"); \
}

template<int OUT_F32>
__global__ __launch_bounds__(512, 2) void k_gemm8(const unsigned short* __restrict__ Ag,
                                                  const unsigned short* __restrict__ Bg,
                                                  const float* __restrict__ bias,
                                                  void* __restrict__ Cout,
                                                  int Ndim, int Kdim){
  extern __shared__ char smem[];
  const int tid = threadIdx.x;
  const int wv = tid >> 6, lane = tid & 63, lg = lane >> 4, lr = lane & 15;
  const int wm = wv >> 2, wn = wv & 3;

  const int nbx = gridDim.x;
  const int nwg = nbx * gridDim.y;
  const int id  = blockIdx.y * nbx + blockIdx.x;
  const int nid = (id & 7) * (nwg >> 3) + (id >> 3);
  const int bx = nid % nbx, by = nid / nbx;
  const int bm0 = by * 256, bn0 = bx * 256;
  const size_t Kb = (size_t)Kdim * 2;
  const int NIT = Kdim >> 7;

  const int srow = tid >> 3;
  const int scb  = ((tid & 7) << 4) ^ ((srow & 7) << 4);
  const char* aS0 = (const char*)Ag + (size_t)(bm0 + srow) * Kb + scb;
  const char* aS1 = (const char*)Ag + (size_t)(bm0 + 128 + srow) * Kb + scb;
  const char* bS0 = (const char*)Bg + (size_t)(bn0 + (srow>>5)*64 + (srow&31)) * Kb + scb;
  const char* bS1 = (const char*)Bg + (size_t)(bn0 + 128 + (srow>>5)*64 + (srow&31)) * Kb + scb;
  char* ldA = smem + wv * 1024;
  char* ldB = smem + 65536 + wv * 1024;

  const int cb0 = (lg * 16) ^ ((lr & 7) << 4);
  const char* rA = smem + (wm*64 + lr) * 128;
  const char* rB = smem + 65536 + (wn*32 + lr) * 128;

  f32x4 acc[8][4];
  #pragma unroll
  for (int i = 0; i < 8; ++i)
    #pragma unroll
    for (int j = 0; j < 4; ++j)
      #pragma unroll
      for (int r = 0; r < 4; ++r) acc[i][j][r] = 0.f;

  bf16x8 af[4][2], bf_[2][2];

  STAGE_A(0,0,0); STAGE_A(0,1,0); STAGE_B(0,0,0); STAGE_B(0,1,0);
  STAGE_A(1,0,1); STAGE_B(1,1,1);
  asm volatile("s_waitcnt vmcnt(4)" ::: "memory");
  __builtin_amdgcn_s_barrier();
  asm volatile("" ::: "memory");

  for (int it = 0; it < NIT; ++it){
    const int T = 2*it;
    PHASE(0, 0,0, 1,1, 0, STAGE_A(1,1,(T+1)))
    PHASE(0, 0,1, 0,1, 0, STAGE_B(1,0,(T+1)))
    PHASE(0, 1,1, 1,0, 0, STAGE_A(0,0,(T+2)))
    PHASE(0, 1,0, 0,1, 1, STAGE_B(0,1,(T+2)))
    PHASE(1, 0,0, 1,1, 0, STAGE_A(0,1,(T+2)))
    PHASE(1, 0,1, 0,1, 0, STAGE_B(0,0,(T+2)))
    PHASE(1, 1,1, 1,0, 0, STAGE_A(1,0,(T+3)))
    PHASE(1, 1,0, 0,1, 1, STAGE_B(1,1,(T+3)))
  }

  #pragma unroll
  for (int RG = 0; RG < 2; ++RG)
    #pragma unroll
    for (int mi = 0; mi < 4; ++mi)
      #pragma unroll
      for (int CG = 0; CG < 2; ++CG)
        #pragma unroll
        for (int ni = 0; ni < 2; ++ni){
          f32x4 v = acc[RG*4+mi][CG*2+ni];
          const int col = bn0 + wn*64 + CG*32 + ni*16 + lr;
          const float bc = bias[col];
          #pragma unroll
          for (int r = 0; r < 4; ++r){
            const int row = bm0 + wm*128 + RG*64 + mi*16 + lg*4 + r;
            const float t = v[r] + bc;
            if (OUT_F32) ((float*)Cout)[(size_t)row * Ndim + col] = t;
            else ((unsigned short*)Cout)[(size_t)row * Ndim + col] = f2bf(t);
          }
        }
}

// ---------------- attention: 2 heads/wave with cross-head prefetch (per-wave, no sync) ----------------
#define ATTN_LOADS(S, hh) \
  const unsigned short* base##S = wb + (hh) * HD; \
  bf16x8 vld##S[4], qf##S[4], kf##S[4]; \
  _Pragma("unroll") for (int t = 0; t < 4; ++t){ \
    int kt = 16*t + vkt; int kts = kt < NTOK ? kt : NTOK-1; \
    vld##S[t] = *(const bf16x8*)(base##S + 1024 + (size_t)kts * O_QKV + vch * 8); } \
  _Pragma("unroll") for (int i = 0; i < 4; ++i){ \
    int t = 16*i + lr; int ts = t < NTOK ? t : NTOK-1; \
    qf##S[i] = *(const bf16x8*)(base##S + (size_t)ts * O_QKV + lg*8); \
    kf##S[i] = *(const bf16x8*)(base##S + 512 + (size_t)ts * O_QKV + lg*8); } \
  const float* bmp##S = bm + (size_t)(wi * NHEAD + (hh)) * (NTOK * 64); \
  f32x4 bias##S[4][4]; \
  _Pragma("unroll") for (int mi = 0; mi < 4; ++mi){ \
    int qt = 16*mi + lr; int qtc = qt < NTOK ? qt : NTOK-1; \
    _Pragma("unroll") for (int ni = 0; ni < 4; ++ni) \
      bias##S[mi][ni] = *(const f32x4*)(bmp##S + qtc*64 + ni*16 + lg*4); }

#define ATTN_QKT(S) \
  __builtin_amdgcn_s_setprio(1); \
  _Pragma("unroll") for (int ni = 0; ni < 4; ++ni) \
    _Pragma("unroll") for (int mi = 0; mi < 4; ++mi) \
      s2[ni][mi] = __builtin_amdgcn_mfma_f32_16x16x32_bf16(kf##S[ni], qf##S[mi], z4, 0, 0, 0); \
  __builtin_amdgcn_s_setprio(0);

#define ATTN_VTWRITE(S) \
  _Pragma("unroll") for (int t = 0; t < 4; ++t){ \
    int kt = 16*t + vkt; \
    _Pragma("unroll") for (int j = 0; j < 8; ++j){ \
      int d = vch*8 + j; \
      int swz = ((d & 7) ^ (d >> 3)) & 7; \
      *(unsigned short*)(Vt + d*128 + ((2*kt) ^ (swz << 4))) = (unsigned short)vld##S[t][j]; } }

#define ATTN_SOFTMAX(S) \
  _Pragma("unroll") for (int mi = 0; mi < 4; ++mi){ \
    float v[4][4]; float mx = -1e30f; \
    _Pragma("unroll") for (int ni = 0; ni < 4; ++ni) \
      _Pragma("unroll") for (int r = 0; r < 4; ++r){ \
        float t = s2[ni][mi][r] * SCALE_F + bias##S[mi][ni][r]; \
        v[ni][r] = t; mx = fmaxf(mx, t); } \
    mx = fmaxf(mx, __shfl_xor(mx, 16)); \
    mx = fmaxf(mx, __shfl_xor(mx, 32)); \
    float sum = 0.f; \
    _Pragma("unroll") for (int ni = 0; ni < 4; ++ni) \
      _Pragma("unroll") for (int r = 0; r < 4; ++r){ \
        float p = __expf(v[ni][r] - mx); v[ni][r] = p; sum += p; } \
    sum += __shfl_xor(sum, 16); sum += __shfl_xor(sum, 32); \
    float rn = 1.0f / sum; \
    const int qt = 16*mi + lr; \
    _Pragma("unroll") for (int ni = 0; ni < 4; ++ni){ \
      uint2 pw; pw.x = pkbf(v[ni][0]*rn, v[ni][1]*rn); pw.y = pkbf(v[ni][2]*rn, v[ni][3]*rn); \
      *(uint2*)(P + qt*128 + ((32*ni + 8*lg) ^ ((lr & 7) << 4))) = pw; } }

#define ATTN_PV_STORE(hh) { \
  f32x4 o[4][2]; \
  _Pragma("unroll") for (int mi = 0; mi < 4; ++mi) \
    _Pragma("unroll") for (int ni = 0; ni < 2; ++ni) \
      _Pragma("unroll") for (int r = 0; r < 4; ++r) o[mi][ni][r] = 0.f; \
  _Pragma("unroll") for (int s = 0; s < 2; ++s){ \
    bf16x8 pf[4], vf[2]; \
    _Pragma("unroll") for (int mi = 0; mi < 4; ++mi) \
      pf[mi] = *(const bf16x8*)(P + (16*mi + lr)*128 + ((64*s + 16*lg) ^ ((lr & 7) << 4))); \
    _Pragma("unroll") for (int ni = 0; ni < 2; ++ni){ \
      int d = 16*ni + lr; int swz = ((d & 7) ^ (d >> 3)) & 7; \
      vf[ni] = *(const bf16x8*)(Vt + d*128 + ((64*s + 16*lg) ^ (swz << 4))); } \
    __builtin_amdgcn_s_setprio(1); \
    _Pragma("unroll") for (int mi = 0; mi < 4; ++mi) \
      _Pragma("unroll") for (int ni = 0; ni < 2; ++ni) \
        o[mi][ni] = __builtin_amdgcn_mfma_f32_16x16x32_bf16(pf[mi], vf[ni], o[mi][ni], 0, 0, 0); \
    __builtin_amdgcn_s_setprio(0); } \
  unsigned short* aop = ao + (size_t)w * NTOK * CDIM + (hh) * HD; \
  _Pragma("unroll") for (int mi = 0; mi < 4; ++mi) \
    _Pragma("unroll") for (int ni = 0; ni < 2; ++ni) \
      _Pragma("unroll") for (int r = 0; r < 4; ++r){ \
        int row = 16*mi + 4*lg + r, col = 16*ni + lr; \
        if (row < NTOK) aop[(size_t)row * CDIM + col] = f2bf(o[mi][ni][r]); } }

__global__ __launch_bounds__(256) void k_attn(const unsigned short* __restrict__ qkv,
                                              const float* __restrict__ bm,
                                              unsigned short* __restrict__ ao){
  __shared__ char lds[4][12288];
  const int wv = threadIdx.x >> 6, lane = threadIdx.x & 63;
  const int lg = lane >> 4, lr = lane & 15;
  const int gw2 = blockIdx.x * 4 + wv;          // 0..16383 (2 heads per wave)
  const int w = gw2 >> 3, h0 = (gw2 & 7) << 1, wi = w & (NWIN - 1);
  char* Vt = lds[wv];
  char* P  = lds[wv] + 4096;
  const unsigned short* wb = qkv + (size_t)w * NTOK * O_QKV;
  const int vkt = lane >> 2, vch = lane & 3;
  f32x4 z4 = {0.f, 0.f, 0.f, 0.f};
  f32x4 s2[4][4];

  // ---- head A: loads + QK^T + Vt + softmax ----
  ATTN_LOADS(A, h0)
  ATTN_QKT(A)
  ATTN_VTWRITE(A)
  ATTN_SOFTMAX(A)
  // ---- head B loads issued here: fly under A's PV + store ----
  ATTN_LOADS(B, h0 + 1)
  // ---- head A: PV + store ----
  ATTN_PV_STORE(h0)
  // ---- head B: compute (Vt reuse is ordered by intra-wave lgkmcnt tracking) ----
  ATTN_QKT(B)
  ATTN_VTWRITE(B)
  ATTN_SOFTMAX(B)
  ATTN_PV_STORE(h0 + 1)
}

// ---------------- launcher ----------------
extern "C" void kernel_launch(void* const* d_in, const int* in_sizes, int n_in,
                              void* d_out, int out_size, void* d_ws, size_t ws_size,
                              hipStream_t stream){
  const float* x      = (const float*)d_in[0];
  const float* mask   = (const float*)d_in[1];
  const float* qkv_w  = (const float*)d_in[2];
  const float* qkv_b  = (const float*)d_in[3];
  const float* proj_w = (const float*)d_in[4];
  const float* proj_b = (const float*)d_in[5];
  const float* rpb    = (const float*)d_in[6];
  const int*   rel_i  = (const int*)d_in[7];

  char* ws = (char*)d_ws;
  unsigned short* xb    = (unsigned short*)(ws);                 // 102,760,448 B (also attn out)
  unsigned short* qkvb  = (unsigned short*)(ws + 102760448);     // 308,281,344 B
  unsigned short* wqkv  = (unsigned short*)(ws + 411041792);     // 1,572,864 B
  unsigned short* wproj = (unsigned short*)(ws + 412614656);     // 524,288 B
  float*          bmb   = (float*)(ws + 413138944);              // 12,845,056 B

  (void)hipFuncSetAttribute(reinterpret_cast<const void*>(&k_gemm8<0>),
                            hipFuncAttributeMaxDynamicSharedMemorySize, 131072);
  (void)hipFuncSetAttribute(reinterpret_cast<const void*>(&k_gemm8<1>),
                            hipFuncAttributeMaxDynamicSharedMemorySize, 131072);

  // 1) x->bf16 + weights->bf16 + bias/mask table (merged)
  k_prep<<<2048, 256, 0, stream>>>(x, qkv_w, proj_w, rpb, rel_i, mask, xb, wqkv, wproj, bmb);
  // 2) QKV GEMM: [100352,1536] = xb * wqkv^T + qkv_b  (bf16 out)
  k_gemm8<0><<<dim3(O_QKV/256, MROWS/256), 512, 131072, stream>>>(xb, wqkv, qkv_b, qkvb, O_QKV, CDIM);
  // 3) attention: 2 heads per wave, 4096 blocks (writes bf16 attn-out into xb region)
  k_attn<<<(B_TOT * NHEAD) / 8, 256, 0, stream>>>(qkvb, bmb, xb);
  // 4) proj GEMM: out[100352,512] = xb * wproj^T + proj_b (f32 out)
  k_gemm8<1><<<dim3(CDIM/256, MROWS/256), 512, 131072, stream>>>(xb, wproj, proj_b, d_out, CDIM, CDIM);
}

// Round 20
// 488.910 us; speedup vs baseline: 1.1140x; 1.1140x over previous
//
#include <hip/hip_runtime.h>
#include <hip/hip_bf16.h>
#include <stdint.h>
#include <stddef.h>

// ---------------- problem constants ----------------
#define B_TOT   2048        // windows total
#define NTOK    49          // tokens per window
#define CDIM    512
#define NHEAD   16
#define HD      32
#define NWIN    64          // windows per image
#define MROWS   (B_TOT*NTOK)   // 100352
#define O_QKV   1536
#define SCALE_F 0.17677669529663687f   // 32^-0.5

typedef short bf16x8 __attribute__((ext_vector_type(8)));
typedef float f32x4  __attribute__((ext_vector_type(4)));

__device__ __forceinline__ unsigned short f2bf(float f){
  union { float f; unsigned u; } v; v.f = f;
  unsigned r = v.u + 0x7fffu + ((v.u >> 16) & 1u);
  return (unsigned short)(r >> 16);
}
__device__ __forceinline__ unsigned pkbf(float a, float b){
  return (unsigned)f2bf(a) | ((unsigned)f2bf(b) << 16);
}

#define GL16(g,l) __builtin_amdgcn_global_load_lds( \
      (const __attribute__((address_space(1))) unsigned int*)(g), \
      (__attribute__((address_space(3))) unsigned int*)(l), 16, 0, 0)

// ---------------- prep: x->bf16, weights->bf16, fused bias+mask table ----------------
__global__ void k_prep(const float* __restrict__ x,
                       const float* __restrict__ qkv_w, const float* __restrict__ proj_w,
                       const float* __restrict__ rpb, const int* __restrict__ rel_idx,
                       const float* __restrict__ mask,
                       unsigned short* __restrict__ xb,
                       unsigned short* __restrict__ wqkv, unsigned short* __restrict__ wproj,
                       float* __restrict__ bmb){
  int i = blockIdx.x * blockDim.x + threadIdx.x;
  int st = gridDim.x * blockDim.x;
  const int n4 = MROWS * CDIM / 4;
  for (int j = i; j < n4; j += st){
    float4 v = ((const float4*)x)[j];
    uint2 o;
    o.x = pkbf(v.x, v.y);
    o.y = pkbf(v.z, v.w);
    ((uint2*)xb)[j] = o;
  }
  for (int j = i; j < O_QKV*CDIM; j += st) wqkv[j] = f2bf(qkv_w[j]);
  for (int j = i; j < CDIM*CDIM;  j += st) wproj[j] = f2bf(proj_w[j]);
  const int TOT = NWIN * NHEAD * NTOK * 64;
  for (int j = i; j < TOT; j += st){
    int wh  = j / (NTOK*64);
    int rem = j - wh * (NTOK*64);
    int qt  = rem >> 6, kt = rem & 63;
    int wi = wh >> 4, h = wh & 15;
    float v;
    if (kt < NTOK){
      int rc = qt * NTOK + kt;
      v = mask[wi * (NTOK*NTOK) + rc] + rpb[rel_idx[rc] * NHEAD + h];
    } else v = -1e30f;
    bmb[j] = v;
  }
}

// ---------------- 8-phase 256x256 GEMM (round-3 schedule, 4/4 validated) ----------------
#define LDA_(P,RG,MI,S) (*(const bf16x8*)(rA + (P)*32768 + (RG)*16384 + (MI)*2048 + ((S)?(cb0^64):cb0)))
#define LDB_(P,CG,NI,S) (*(const bf16x8*)(rB + (P)*32768 + (CG)*16384 + (NI)*2048 + ((S)?(cb0^64):cb0)))

#define STAGE_A(P,HG,KT) { \
    GL16(aS0 + (size_t)(HG)*64*Kb + (size_t)(KT)*128, ldA + (P)*32768 + (HG)*16384); \
    GL16(aS1 + (size_t)(HG)*64*Kb + (size_t)(KT)*128, ldA + (P)*32768 + (HG)*16384 + 8192); }
#define STAGE_B(P,HG,KT) { \
    GL16(bS0 + (size_t)(HG)*32*Kb + (size_t)(KT)*128, ldB + (P)*32768 + (HG)*16384); \
    GL16(bS1 + (size_t)(HG)*32*Kb + (size_t)(KT)*128, ldB + (P)*32768 + (HG)*16384 + 8192); }

#define PHASE(P,RG,CG,DOA,DOB,VM,...) { \
  if (DOA){ _Pragma("unroll") for (int mi=0;mi<4;++mi){ af[mi][0]=LDA_(P,RG,mi,0); af[mi][1]=LDA_(P,RG,mi,1);} } \
  if (DOB){ _Pragma("unroll") for (int ni=0;ni<2;++ni){ bf_[ni][0]=LDB_(P,CG,ni,0); bf_[ni][1]=LDB_(P,CG,ni,1);} } \
  __VA_ARGS__; \
  __builtin_amdgcn_s_barrier(); \
  asm volatile("s_waitcnt lgkmcnt(0)" ::: "memory"); \
  __builtin_amdgcn_sched_barrier(0); \
  __builtin_amdgcn_s_setprio(1); \
  _Pragma("unroll") for (int s=0;s<2;++s) \
    _Pragma("unroll") for (int mi=0;mi<4;++mi) \
      _Pragma("unroll") for (int ni=0;ni<2;++ni) \
        acc[(RG)*4+mi][(CG)*2+ni] = __builtin_amdgcn_mfma_f32_16x16x32_bf16(af[mi][s], bf_[ni][s], acc[(RG)*4+mi][(CG)*2+ni], 0,0,0); \
  __builtin_amdgcn_s_setprio(0); \
  if (VM) asm volatile("s_waitcnt vmcnt(4)" ::: "memory"); \
  __builtin_amdgcn_s_barrier(); \
  asm volatile("" ::: "memory"); \
}

template<int OUT_F32>
__global__ __launch_bounds__(512, 2) void k_gemm8(const unsigned short* __restrict__ Ag,
                                                  const unsigned short* __restrict__ Bg,
                                                  const float* __restrict__ bias,
                                                  void* __restrict__ Cout,
                                                  int Ndim, int Kdim){
  extern __shared__ char smem[];
  const int tid = threadIdx.x;
  const int wv = tid >> 6, lane = tid & 63, lg = lane >> 4, lr = lane & 15;
  const int wm = wv >> 2, wn = wv & 3;

  const int nbx = gridDim.x;
  const int nwg = nbx * gridDim.y;
  const int id  = blockIdx.y * nbx + blockIdx.x;
  const int nid = (id & 7) * (nwg >> 3) + (id >> 3);
  const int bx = nid % nbx, by = nid / nbx;
  const int bm0 = by * 256, bn0 = bx * 256;
  const size_t Kb = (size_t)Kdim * 2;
  const int NIT = Kdim >> 7;

  const int srow = tid >> 3;
  const int scb  = ((tid & 7) << 4) ^ ((srow & 7) << 4);
  const char* aS0 = (const char*)Ag + (size_t)(bm0 + srow) * Kb + scb;
  const char* aS1 = (const char*)Ag + (size_t)(bm0 + 128 + srow) * Kb + scb;
  const char* bS0 = (const char*)Bg + (size_t)(bn0 + (srow>>5)*64 + (srow&31)) * Kb + scb;
  const char* bS1 = (const char*)Bg + (size_t)(bn0 + 128 + (srow>>5)*64 + (srow&31)) * Kb + scb;
  char* ldA = smem + wv * 1024;
  char* ldB = smem + 65536 + wv * 1024;

  const int cb0 = (lg * 16) ^ ((lr & 7) << 4);
  const char* rA = smem + (wm*64 + lr) * 128;
  const char* rB = smem + 65536 + (wn*32 + lr) * 128;

  f32x4 acc[8][4];
  #pragma unroll
  for (int i = 0; i < 8; ++i)
    #pragma unroll
    for (int j = 0; j < 4; ++j)
      #pragma unroll
      for (int r = 0; r < 4; ++r) acc[i][j][r] = 0.f;

  bf16x8 af[4][2], bf_[2][2];

  STAGE_A(0,0,0); STAGE_A(0,1,0); STAGE_B(0,0,0); STAGE_B(0,1,0);
  STAGE_A(1,0,1); STAGE_B(1,1,1);
  asm volatile("s_waitcnt vmcnt(4)" ::: "memory");
  __builtin_amdgcn_s_barrier();
  asm volatile("" ::: "memory");

  for (int it = 0; it < NIT; ++it){
    const int T = 2*it;
    PHASE(0, 0,0, 1,1, 0, STAGE_A(1,1,(T+1)))
    PHASE(0, 0,1, 0,1, 0, STAGE_B(1,0,(T+1)))
    PHASE(0, 1,1, 1,0, 0, STAGE_A(0,0,(T+2)))
    PHASE(0, 1,0, 0,1, 1, STAGE_B(0,1,(T+2)))
    PHASE(1, 0,0, 1,1, 0, STAGE_A(0,1,(T+2)))
    PHASE(1, 0,1, 0,1, 0, STAGE_B(0,0,(T+2)))
    PHASE(1, 1,1, 1,0, 0, STAGE_A(1,0,(T+3)))
    PHASE(1, 1,0, 0,1, 1, STAGE_B(1,1,(T+3)))
  }

  #pragma unroll
  for (int RG = 0; RG < 2; ++RG)
    #pragma unroll
    for (int mi = 0; mi < 4; ++mi)
      #pragma unroll
      for (int CG = 0; CG < 2; ++CG)
        #pragma unroll
        for (int ni = 0; ni < 2; ++ni){
          f32x4 v = acc[RG*4+mi][CG*2+ni];
          const int col = bn0 + wn*64 + CG*32 + ni*16 + lr;
          const float bc = bias[col];
          #pragma unroll
          for (int r = 0; r < 4; ++r){
            const int row = bm0 + wm*128 + RG*64 + mi*16 + lg*4 + r;
            const float t = v[r] + bc;
            if (OUT_F32) ((float*)Cout)[(size_t)row * Ndim + col] = t;
            else ((unsigned short*)Cout)[(size_t)row * Ndim + col] = f2bf(t);
          }
        }
}

// ---------------- attention (round-3 verified + T5 setprio on MFMA clusters) ----------------
__global__ __launch_bounds__(256) void k_attn(const unsigned short* __restrict__ qkv,
                                              const float* __restrict__ bm,
                                              unsigned short* __restrict__ ao){
  __shared__ char lds[4][12288];
  const int wv = threadIdx.x >> 6, lane = threadIdx.x & 63;
  const int lg = lane >> 4, lr = lane & 15;
  const int gw = blockIdx.x * 4 + wv;
  const int w = gw >> 4, h = gw & 15, wi = w & (NWIN - 1);
  char* Vt = lds[wv];
  char* P  = lds[wv] + 4096;

  const unsigned short* base = qkv + (size_t)w * NTOK * O_QKV + h * HD;

  const int vkt = lane >> 2, vch = lane & 3;
  bf16x8 vld[4];
  #pragma unroll
  for (int t = 0; t < 4; ++t){
    int kt = 16*t + vkt; int kts = kt < NTOK ? kt : NTOK-1;
    vld[t] = *(const bf16x8*)(base + 1024 + (size_t)kts * O_QKV + vch * 8);
  }

  bf16x8 qf[4], kf[4];
  #pragma unroll
  for (int i = 0; i < 4; ++i){
    int t = 16*i + lr; int ts = t < NTOK ? t : NTOK-1;
    qf[i] = *(const bf16x8*)(base + (size_t)ts * O_QKV + lg*8);
    kf[i] = *(const bf16x8*)(base + 512 + (size_t)ts * O_QKV + lg*8);
  }

  const float* bmp = bm + (size_t)(wi * NHEAD + h) * (NTOK * 64);
  f32x4 bias[4][4];
  #pragma unroll
  for (int mi = 0; mi < 4; ++mi){
    int qt = 16*mi + lr; int qtc = qt < NTOK ? qt : NTOK-1;
    #pragma unroll
    for (int ni = 0; ni < 4; ++ni)
      bias[mi][ni] = *(const f32x4*)(bmp + qtc*64 + ni*16 + lg*4);
  }

  f32x4 z4 = {0.f, 0.f, 0.f, 0.f};
  f32x4 s2[4][4];
  __builtin_amdgcn_s_setprio(1);
  #pragma unroll
  for (int ni = 0; ni < 4; ++ni)
    #pragma unroll
    for (int mi = 0; mi < 4; ++mi)
      s2[ni][mi] = __builtin_amdgcn_mfma_f32_16x16x32_bf16(kf[ni], qf[mi], z4, 0, 0, 0);
  __builtin_amdgcn_s_setprio(0);

  #pragma unroll
  for (int t = 0; t < 4; ++t){
    int kt = 16*t + vkt;
    #pragma unroll
    for (int j = 0; j < 8; ++j){
      int d = vch*8 + j;
      int swz = ((d & 7) ^ (d >> 3)) & 7;
      int byte = d*128 + ((2*kt) ^ (swz << 4));
      *(unsigned short*)(Vt + byte) = (unsigned short)vld[t][j];
    }
  }

  #pragma unroll
  for (int mi = 0; mi < 4; ++mi){
    float v[4][4];
    float mx = -1e30f;
    #pragma unroll
    for (int ni = 0; ni < 4; ++ni)
      #pragma unroll
      for (int r = 0; r < 4; ++r){
        float t = s2[ni][mi][r] * SCALE_F + bias[mi][ni][r];
        v[ni][r] = t;
        mx = fmaxf(mx, t);
      }
    mx = fmaxf(mx, __shfl_xor(mx, 16));
    mx = fmaxf(mx, __shfl_xor(mx, 32));
    float sum = 0.f;
    #pragma unroll
    for (int ni = 0; ni < 4; ++ni)
      #pragma unroll
      for (int r = 0; r < 4; ++r){
        float p = __expf(v[ni][r] - mx);
        v[ni][r] = p;
        sum += p;
      }
    sum += __shfl_xor(sum, 16);
    sum += __shfl_xor(sum, 32);
    float rn = 1.0f / sum;
    const int qt = 16*mi + lr;
    #pragma unroll
    for (int ni = 0; ni < 4; ++ni){
      uint2 pw;
      pw.x = pkbf(v[ni][0]*rn, v[ni][1]*rn);
      pw.y = pkbf(v[ni][2]*rn, v[ni][3]*rn);
      int byte = qt*128 + ((32*ni + 8*lg) ^ ((lr & 7) << 4));
      *(uint2*)(P + byte) = pw;
    }
  }

  f32x4 o[4][2];
  #pragma unroll
  for (int mi = 0; mi < 4; ++mi)
    #pragma unroll
    for (int ni = 0; ni < 2; ++ni)
      #pragma unroll
      for (int r = 0; r < 4; ++r) o[mi][ni][r] = 0.f;

  #pragma unroll
  for (int s = 0; s < 2; ++s){
    bf16x8 pf[4], vf[2];
    #pragma unroll
    for (int mi = 0; mi < 4; ++mi)
      pf[mi] = *(const bf16x8*)(P + (16*mi + lr)*128 + ((64*s + 16*lg) ^ ((lr & 7) << 4)));
    #pragma unroll
    for (int ni = 0; ni < 2; ++ni){
      int d = 16*ni + lr;
      int swz = ((d & 7) ^ (d >> 3)) & 7;
      vf[ni] = *(const bf16x8*)(Vt + d*128 + ((64*s + 16*lg) ^ (swz << 4)));
    }
    __builtin_amdgcn_s_setprio(1);
    #pragma unroll
    for (int mi = 0; mi < 4; ++mi)
      #pragma unroll
      for (int ni = 0; ni < 2; ++ni)
        o[mi][ni] = __builtin_amdgcn_mfma_f32_16x16x32_bf16(pf[mi], vf[ni], o[mi][ni], 0, 0, 0);
    __builtin_amdgcn_s_setprio(0);
  }

  unsigned short* aop = ao + (size_t)w * NTOK * CDIM + h * HD;
  #pragma unroll
  for (int mi = 0; mi < 4; ++mi)
    #pragma unroll
    for (int ni = 0; ni < 2; ++ni)
      #pragma unroll
      for (int r = 0; r < 4; ++r){
        int row = 16*mi + 4*lg + r, col = 16*ni + lr;
        if (row < NTOK)
          aop[(size_t)row * CDIM + col] = f2bf(o[mi][ni][r]);
      }
}

// ---------------- launcher ----------------
extern "C" void kernel_launch(void* const* d_in, const int* in_sizes, int n_in,
                              void* d_out, int out_size, void* d_ws, size_t ws_size,
                              hipStream_t stream){
  const float* x      = (const float*)d_in[0];
  const float* mask   = (const float*)d_in[1];
  const float* qkv_w  = (const float*)d_in[2];
  const float* qkv_b  = (const float*)d_in[3];
  const float* proj_w = (const float*)d_in[4];
  const float* proj_b = (const float*)d_in[5];
  const float* rpb    = (const float*)d_in[6];
  const int*   rel_i  = (const int*)d_in[7];

  char* ws = (char*)d_ws;
  unsigned short* xb    = (unsigned short*)(ws);                 // 102,760,448 B (also attn out)
  unsigned short* qkvb  = (unsigned short*)(ws + 102760448);     // 308,281,344 B
  unsigned short* wqkv  = (unsigned short*)(ws + 411041792);     // 1,572,864 B
  unsigned short* wproj = (unsigned short*)(ws + 412614656);     // 524,288 B
  float*          bmb   = (float*)(ws + 413138944);              // 12,845,056 B

  (void)hipFuncSetAttribute(reinterpret_cast<const void*>(&k_gemm8<0>),
                            hipFuncAttributeMaxDynamicSharedMemorySize, 131072);
  (void)hipFuncSetAttribute(reinterpret_cast<const void*>(&k_gemm8<1>),
                            hipFuncAttributeMaxDynamicSharedMemorySize, 131072);

  // 1) x->bf16 + weights->bf16 + bias/mask table (merged)
  k_prep<<<2048, 256, 0, stream>>>(x, qkv_w, proj_w, rpb, rel_i, mask, xb, wqkv, wproj, bmb);
  // 2) QKV GEMM: [100352,1536] = xb * wqkv^T + qkv_b  (bf16 out)
  k_gemm8<0><<<dim3(O_QKV/256, MROWS/256), 512, 131072, stream>>>(xb, wqkv, qkv_b, qkvb, O_QKV, CDIM);
  // 3) attention (writes bf16 attn-out into xb region)
  k_attn<<<(B_TOT * NHEAD) / 4, 256, 0, stream>>>(qkvb, bmb, xb);
  // 4) proj GEMM: out[100352,512] = xb * wproj^T + proj_b (f32 out)
  k_gemm8<1><<<dim3(CDIM/256, MROWS/256), 512, 131072, stream>>>(xb, wproj, proj_b, d_out, CDIM, CDIM);
}